// Round 11
// baseline (504.824 us; speedup 1.0000x reference)
//
#include <hip/hip_runtime.h>
#include <hip/hip_bf16.h>

// GraphSAGE 2-layer, N=100000, E=1.6M, D=128. f32 I/O, bf16 MFMA compute.
//
// R18: direct-atomic CSR. R17 post-mortem: no-LDS gemm neutral (-7.5us) ->
// gemm near floor; revert to R12 gemm. Remaining lever: the bucketed CSR
// moves every edge 3x (dst read, bucketBuf write+read, sortedSrc write)
// ~80us. R11 proved random 4B scatters are cheap; within-node edge order
// has ALWAYS been nondeterministic (LDS-atomic arrival) with absmax
// byte-identical across all variants -> order-insensitive. So:
//   memset(deg,bar) -> deg_cvt (deg[dst]++ atomics | x->bf16 cvt tails)
//   -> scan_offs (ONE dispatch, 391 tiny blocks + 2 grid barriers; the
//      one safe place for R13-style fusion: latency-bound scan, no
//      streaming) -> scatter+wprep (sortedSrc[atomicAdd(&cur[dst],1)]=src).
// Deletes bucketBuf/hist/baseT entirely. agg at 2-fills/edge cap (69.5us),
// gemm/agg byte-identical to R12 (345.8 best).
//
// Pipeline (8 dispatches): memset -> deg_cvt -> scan_offs -> scatter+wprep
//   -> agg1 -> gemm1(relu->h1b) -> agg2 -> gemm2 -> d_out f32.
//   Fallback layout B (small ws): f32 gathers, h1 f32 staged in d_out.

typedef __attribute__((ext_vector_type(8))) short short8;
typedef __attribute__((ext_vector_type(4))) float float4_;

#define NBMAX 512  // max 256-node scan blocks -> N <= 131072

__device__ __forceinline__ unsigned short f2bf(float f) {
    unsigned int u = __float_as_uint(f);
    unsigned int r = (u + 0x7FFFu + ((u >> 16) & 1u)) >> 16;
    return (unsigned short)r;
}

// Software grid barrier: monotonic counter (bar zeroed by host memset).
__device__ __forceinline__ void gbar(int* bar, int id, int G) {
    __syncthreads();
    if (threadIdx.x == 0) {
        __threadfence();
        atomicAdd(&bar[id], 1);
        while (atomicAdd(&bar[id], 0) < G) __builtin_amdgcn_s_sleep(16);
        __threadfence();
    }
    __syncthreads();
}

// ---------------- phase 1: deg count (+ tail blocks: x->bf16 cvt) ----------
__global__ __launch_bounds__(256) void deg_cvt(
    const int* __restrict__ dst, int E, int cntBlocks, int* __restrict__ deg,
    const float* __restrict__ xin, unsigned int* __restrict__ xb, int n2) {
    int tid = threadIdx.x;
    if ((int)blockIdx.x >= cntBlocks) {
        // ---- cvt: f32 [N,128] -> packed bf16 u32 [N,64], 8 u32/thread ----
        int cb = blockIdx.x - cntBlocks;
        int base = cb * 2048 + tid;
        if (xb) {
#pragma unroll
            for (int i = 0; i < 8; i++) {
                int t = base + i * 256;
                if (t < n2) {
                    float2 v = ((const float2*)xin)[t];
                    xb[t] = (unsigned)f2bf(v.x) | ((unsigned)f2bf(v.y) << 16);
                }
            }
        }
        return;
    }
    int base = blockIdx.x * 4096;
    for (int i = 0; i < 16; i++) {
        int e = base + i * 256 + tid;
        if (e < E) atomicAdd(&deg[dst[e]], 1);
    }
}

// ---------------- phase 2: scan deg -> offs, cur (one dispatch) ------------
// G = NBv = ceil(N/256) <= 512 blocks, co-resident by construction (tiny
// LDS, 256 thr). Ph1: block-scan 256 degs -> partial[b]. gbar. Ph2: block 0
// scans partials (two 256-halves). gbar. Ph3: offs/cur = base + excl.
__global__ __launch_bounds__(256) void scan_offs(
    const int* __restrict__ deg, int N, int NBv, int G,
    int* __restrict__ partialS, int* __restrict__ gBase,
    int* __restrict__ offs, int* __restrict__ cur, int* __restrict__ bar) {
    __shared__ int sc[256];
    int b = blockIdx.x, tid = threadIdx.x;
    int n = b * 256 + tid;
    int v = (n < N) ? deg[n] : 0;
    sc[tid] = v;
    __syncthreads();
    for (int off = 1; off < 256; off <<= 1) {
        int x = sc[tid];
        int y = (tid >= off) ? sc[tid - off] : 0;
        __syncthreads();
        sc[tid] = x + y;
        __syncthreads();
    }
    int excl = sc[tid] - v;
    if (tid == 0) partialS[b] = sc[255];
    gbar(bar, 0, G);
    if (b == 0) {
        int v0 = (tid < NBv) ? partialS[tid] : 0;
        int j = 256 + tid;
        int v1 = (j < NBv) ? partialS[j] : 0;
        sc[tid] = v0;
        __syncthreads();
        for (int off = 1; off < 256; off <<= 1) {
            int x = sc[tid];
            int y = (tid >= off) ? sc[tid - off] : 0;
            __syncthreads();
            sc[tid] = x + y;
            __syncthreads();
        }
        int inc0 = sc[tid];
        int tot0 = sc[255];
        __syncthreads();
        sc[tid] = v1;
        __syncthreads();
        for (int off = 1; off < 256; off <<= 1) {
            int x = sc[tid];
            int y = (tid >= off) ? sc[tid - off] : 0;
            __syncthreads();
            sc[tid] = x + y;
            __syncthreads();
        }
        int inc1 = sc[tid];
        __syncthreads();
        gBase[tid] = inc0 - v0;
        gBase[j] = tot0 + inc1 - v1;
    }
    gbar(bar, 1, G);
    int base = gBase[b];
    if (n < N) {
        int o = base + excl;
        offs[n] = o;
        cur[n] = o;
    }
}

// ---------------- phase 3: scatter edges + (tail blocks) weight prep -------
__global__ __launch_bounds__(256) void scatter_wprep(
    const int* __restrict__ src, const int* __restrict__ dst, int E, int partBlocks,
    int* __restrict__ cur, int* __restrict__ sortedSrc,
    const float* __restrict__ Wn1, const float* __restrict__ Ws1,
    const float* __restrict__ bn1, const float* __restrict__ bs1,
    const float* __restrict__ Wn2, const float* __restrict__ Ws2,
    const float* __restrict__ bn2, const float* __restrict__ bs2,
    unsigned short* __restrict__ Bpre, float* __restrict__ biasPre) {
    int tid = threadIdx.x;
    if ((int)blockIdx.x >= partBlocks) {
        // ---- weight prep: f32 W -> bf16 pre-swizzled fragments ----
        int wb = blockIdx.x - partBlocks;  // [0,32)
        int l = wb >> 4;
        const float* Wn = l ? Wn2 : Wn1;
        const float* Ws = l ? Ws2 : Ws1;
        int fi = (wb & 15) * 256 + tid;
        int kt = fi >> 9;
        int nt = (fi >> 6) & 7;
        int lane = fi & 63;
        int o = nt * 16 + (lane & 15);
        int k = kt * 32 + (lane >> 4) * 8;
        const float* srcp = (k < 128) ? (Wn + o * 128 + k) : (Ws + o * 128 + (k - 128));
        short8 v;
#pragma unroll
        for (int j = 0; j < 8; j++) v[j] = (short)f2bf(srcp[j]);
        ((short8*)(Bpre + (size_t)l * 32768))[fi] = v;
        if ((wb & 15) == 0 && tid < 128) {
            const float* bn = l ? bn2 : bn1;
            const float* bs = l ? bs2 : bs1;
            biasPre[l * 128 + tid] = bn[tid] + bs[tid];
        }
        return;
    }
    int eb = blockIdx.x * 4096;
    for (int i = 0; i < 16; i++) {
        int e = eb + i * 256 + tid;
        if (e < E) {
            int d = dst[e];
            int pos = atomicAdd(&cur[d], 1);
            sortedSrc[pos] = src[e];
        }
    }
}

// ---------------- mean agg, bf16 source (wave/node, 16-deep, SGPR bases) ----
__global__ __launch_bounds__(256) void agg_bf16_kernel(
    const unsigned int* __restrict__ srcFeats,
    const int* __restrict__ deg, const int* __restrict__ offs,
    const int* __restrict__ sortedSrc,
    unsigned int* __restrict__ dst, int Nn) {
    int wave = threadIdx.x >> 6, lane = threadIdx.x & 63;
    int n = blockIdx.x * 4 + wave;
    if (n >= Nn) return;
    int d = deg[n], st = offs[n];
    float a0 = 0.f, a1 = 0.f;
    int j = 0;
    for (; j + 16 <= d; j += 16) {
        unsigned int uu[16];
#pragma unroll
        for (int u = 0; u < 16; u++) {
            int s = __builtin_amdgcn_readfirstlane(sortedSrc[st + j + u]);
            uu[u] = (srcFeats + (size_t)s * 64)[lane];
        }
#pragma unroll
        for (int u = 0; u < 16; u++) {
            a0 += __uint_as_float(uu[u] << 16);
            a1 += __uint_as_float(uu[u] & 0xFFFF0000u);
        }
    }
    for (; j + 8 <= d; j += 8) {
        unsigned int uu[8];
#pragma unroll
        for (int u = 0; u < 8; u++) {
            int s = __builtin_amdgcn_readfirstlane(sortedSrc[st + j + u]);
            uu[u] = (srcFeats + (size_t)s * 64)[lane];
        }
#pragma unroll
        for (int u = 0; u < 8; u++) {
            a0 += __uint_as_float(uu[u] << 16);
            a1 += __uint_as_float(uu[u] & 0xFFFF0000u);
        }
    }
    for (; j < d; j++) {
        int s = __builtin_amdgcn_readfirstlane(sortedSrc[st + j]);
        unsigned int u = (srcFeats + (size_t)s * 64)[lane];
        a0 += __uint_as_float(u << 16);
        a1 += __uint_as_float(u & 0xFFFF0000u);
    }
    float inv = 1.0f / (float)max(d, 1);
    dst[(size_t)n * 64 + lane] = (unsigned)f2bf(a0 * inv) | ((unsigned)f2bf(a1 * inv) << 16);
}

// ---------------- mean agg, f32 source (fallback layout B) ------------------
__global__ __launch_bounds__(256) void agg_f32_kernel(
    const float* __restrict__ srcFeats,
    const int* __restrict__ deg, const int* __restrict__ offs,
    const int* __restrict__ sortedSrc,
    unsigned int* __restrict__ dst, int Nn) {
    int wave = threadIdx.x >> 6, lane = threadIdx.x & 63;
    int n = blockIdx.x * 4 + wave;
    if (n >= Nn) return;
    int d = deg[n], st = offs[n];
    float a0 = 0.f, a1 = 0.f;
    int j = 0;
    for (; j + 8 <= d; j += 8) {
        float2 v[8];
#pragma unroll
        for (int u = 0; u < 8; u++) {
            int s = __builtin_amdgcn_readfirstlane(sortedSrc[st + j + u]);
            v[u] = ((const float2*)(srcFeats + (size_t)s * 128))[lane];
        }
#pragma unroll
        for (int u = 0; u < 8; u++) {
            a0 += v[u].x;
            a1 += v[u].y;
        }
    }
    for (; j < d; j++) {
        int s = __builtin_amdgcn_readfirstlane(sortedSrc[st + j]);
        float2 v = ((const float2*)(srcFeats + (size_t)s * 128))[lane];
        a0 += v.x;
        a1 += v.y;
    }
    float inv = 1.0f / (float)max(d, 1);
    dst[(size_t)n * 64 + lane] = (unsigned)f2bf(a0 * inv) | ((unsigned)f2bf(a1 * inv) << 16);
}

// ---------------- fused GEMM: out = act([Aagg|Aself] @ B^T + bias) ---------
// R12 version (proven 345.8): 64KB LDS B-tile, inner-loop A loads.
// Out may alias Aself (fallback layer 2): each wave reads only its own 32
// rows before writing them -> safe. (No __restrict__ on Aself/Out.)
__global__ __launch_bounds__(256) void gemm_kernel(
    const unsigned short* __restrict__ Aagg, const void* Aself,
    const unsigned short* __restrict__ Bpre, const float* __restrict__ biasPre,
    void* Out, int relu, int selfF32, int outBf16, int Nrows) {
    __shared__ unsigned short ldsB[8 * 8 * 64 * 8];  // 64 KB
    __shared__ float biasS[128];
    int tid = threadIdx.x;

#pragma unroll
    for (int i = 0; i < 16; i++) {
        int fi = tid + 256 * i;
        ((short8*)ldsB)[fi] = ((const short8*)Bpre)[fi];
    }
    if (tid < 128) biasS[tid] = biasPre[tid];
    __syncthreads();

    int wave = tid >> 6, lane = tid & 63;
    int quad = lane >> 4, mr = lane & 15;
    int rowBase = blockIdx.x * 128 + wave * 32;

    float4_ acc[2][8];
    float4_ z = {0.f, 0.f, 0.f, 0.f};
    for (int mt = 0; mt < 2; mt++)
        for (int nt = 0; nt < 8; nt++) acc[mt][nt] = z;

    for (int kt = 0; kt < 8; kt++) {
        int kk = (kt & 3) * 32 + quad * 8;
        short8 a[2];
        for (int mt = 0; mt < 2; mt++) {
            int row = rowBase + mt * 16 + mr;
            if (row >= Nrows) row = Nrows - 1;  // in-bounds; result discarded
            if (kt < 4) {
                a[mt] = *(const short8*)(Aagg + (size_t)row * 128 + kk);
            } else if (selfF32) {
                const float* p = (const float*)Aself + (size_t)row * 128 + kk;
                float4_ f0 = *(const float4_*)p;
                float4_ f1 = *(const float4_*)(p + 4);
                short8 t;
#pragma unroll
                for (int j = 0; j < 4; j++) {
                    t[j] = (short)f2bf(f0[j]);
                    t[4 + j] = (short)f2bf(f1[j]);
                }
                a[mt] = t;
            } else {
                a[mt] = *(const short8*)((const unsigned short*)Aself + (size_t)row * 128 + kk);
            }
        }
        for (int nt = 0; nt < 8; nt++) {
            short8 b = *(const short8*)(ldsB + ((size_t)(kt * 8 + nt) * 64 + lane) * 8);
            acc[0][nt] = __builtin_amdgcn_mfma_f32_16x16x32_bf16(a[0], b, acc[0][nt], 0, 0, 0);
            acc[1][nt] = __builtin_amdgcn_mfma_f32_16x16x32_bf16(a[1], b, acc[1][nt], 0, 0, 0);
        }
    }

    // C/D layout: col = lane&15, row = (lane>>4)*4 + reg
    for (int mt = 0; mt < 2; mt++) {
        for (int nt = 0; nt < 8; nt++) {
            int col = nt * 16 + mr;
            float bv = biasS[col];
            for (int r = 0; r < 4; r++) {
                int row = rowBase + mt * 16 + quad * 4 + r;
                if (row < Nrows) {
                    float v = acc[mt][nt][r] + bv;
                    if (relu) v = fmaxf(v, 0.f);
                    if (outBf16)
                        ((unsigned short*)Out)[(size_t)row * 128 + col] = f2bf(v);
                    else
                        ((float*)Out)[(size_t)row * 128 + col] = v;
                }
            }
        }
    }
}

extern "C" void kernel_launch(void* const* d_in, const int* in_sizes, int n_in,
                              void* d_out, int out_size, void* d_ws, size_t ws_size,
                              hipStream_t stream) {
    const float* x = (const float*)d_in[0];
    const int* ei = (const int*)d_in[1];
    const float* Wn1 = (const float*)d_in[2];
    const float* bn1 = (const float*)d_in[3];
    const float* Ws1 = (const float*)d_in[4];
    const float* bs1 = (const float*)d_in[5];
    const float* Wn2 = (const float*)d_in[6];
    const float* bn2 = (const float*)d_in[7];
    const float* Ws2 = (const float*)d_in[8];
    const float* bs2 = (const float*)d_in[9];

    const int N = in_sizes[0] / 128;
    const int E = in_sizes[1] / 2;
    const int* srcI = ei;
    const int* dstI = ei + E;
    const int ebBlocks = (E + 4095) / 4096;
    const int NBv = (N + 255) >> 8;  // <= NBMAX for N <= 131072

    char* ws = (char*)d_ws;
    size_t off = 0;
    auto alloc = [&](size_t bytes) -> void* {
        void* p = ws + off;
        off += (bytes + 255) & ~(size_t)255;
        return p;
    };
    int* deg = (int*)alloc((size_t)N * 4);      // zeroed (memset below)
    int* bar = (int*)alloc(64);                 // zeroed (same memset)
    size_t zeroBytes = off;                     // deg (padded) + bar
    int* offs = (int*)alloc((size_t)N * 4);
    int* cur = (int*)alloc((size_t)N * 4);
    int* partialS = (int*)alloc(NBMAX * 4);
    int* gBase = (int*)alloc(NBMAX * 4);
    unsigned short* Bpre = (unsigned short*)alloc(2 * 32768 * 2);
    float* biasPre = (float*)alloc(2 * 128 * 4);
    int* sortedSrc = (int*)alloc((size_t)E * 4);
    unsigned short* Aagg = (unsigned short*)alloc((size_t)N * 128 * 2);
    size_t baseNeed = off;
    size_t bf16Buf = ((size_t)N * 128 * 2 + 255) & ~(size_t)255;
    bool bigWs = (ws_size >= baseNeed + 2 * bf16Buf);
    unsigned int* xb = nullptr;
    unsigned short* h1b = nullptr;
    if (bigWs) {
        xb = (unsigned int*)alloc((size_t)N * 128 * 2);
        h1b = (unsigned short*)alloc((size_t)N * 128 * 2);
    }

    // ---- CSR build: direct-atomic (deg count -> scan -> scatter) ----
    int n2 = N * 64;
    int cvtBlocks = bigWs ? (n2 + 2047) / 2048 : 0;
    hipMemsetAsync(deg, 0, zeroBytes, stream);  // deg + bar
    deg_cvt<<<ebBlocks + cvtBlocks, 256, 0, stream>>>(dstI, E, ebBlocks, deg, x, xb, n2);
    scan_offs<<<NBv, 256, 0, stream>>>(deg, N, NBv, NBv, partialS, gBase, offs, cur, bar);
    scatter_wprep<<<ebBlocks + 32, 256, 0, stream>>>(
        srcI, dstI, E, ebBlocks, cur, sortedSrc,
        Wn1, Ws1, bn1, bs1, Wn2, Ws2, bn2, bs2, Bpre, biasPre);

    int aggBlocks = (N + 3) / 4;
    int gemmBlocks = (N + 127) / 128;

    if (bigWs) {
        // Layout A: all gathers bf16 (256 B/row)
        agg_bf16_kernel<<<aggBlocks, 256, 0, stream>>>(xb, deg, offs, sortedSrc,
                                                       (unsigned int*)Aagg, N);
        gemm_kernel<<<gemmBlocks, 256, 0, stream>>>(Aagg, xb, Bpre, biasPre, h1b, 1, 0, 1, N);
        agg_bf16_kernel<<<aggBlocks, 256, 0, stream>>>((const unsigned int*)h1b, deg, offs,
                                                       sortedSrc, (unsigned int*)Aagg, N);
        gemm_kernel<<<gemmBlocks, 256, 0, stream>>>(Aagg, h1b, Bpre + 32768, biasPre + 128,
                                                    d_out, 0, 0, 0, N);
    } else {
        // Layout B: f32 gathers, h1 f32 staged in d_out
        float* h1 = (float*)d_out;
        agg_f32_kernel<<<aggBlocks, 256, 0, stream>>>(x, deg, offs, sortedSrc,
                                                      (unsigned int*)Aagg, N);
        gemm_kernel<<<gemmBlocks, 256, 0, stream>>>(Aagg, x, Bpre, biasPre, h1, 1, 1, 0, N);
        agg_f32_kernel<<<aggBlocks, 256, 0, stream>>>(h1, deg, offs, sortedSrc,
                                                      (unsigned int*)Aagg, N);
        gemm_kernel<<<gemmBlocks, 256, 0, stream>>>(Aagg, h1, Bpre + 32768, biasPre + 128,
                                                    d_out, 0, 1, 0, N);
    }
}

// Round 12
// 348.333 us; speedup vs baseline: 1.4493x; 1.4493x over previous
//
#include <hip/hip_runtime.h>
#include <hip/hip_bf16.h>

// GraphSAGE 2-layer, N=100000, E=1.6M, D=128. f32 I/O, bf16 MFMA compute.
//
// R19 = verbatim revert to R12 (measured best: 345.8us). R18 post-mortem:
// direct-atomic scatter = 150us (return-value atomicAdd RMW round-trips,
// VALUBusy 0.27%) -> bucketed CSR is the right structure. Full budget map
// after 11 rounds: aggs 139us (HW L1-fill cap, 2 fills/edge @ ~0.073
// fills/cy/CU; HBM only 38% used), gaps ~37us (5.3us each, measured R16),
// gemms <40us each (2 restructures neutral), CSR ~85us (3 restructures all
// negative; this atomic-free bucketing is best). Every slice has resisted
// >=2 independent attacks -> structural roofline candidate.
//
// Pipeline (9 dispatches): bucket_count -> blk_scan -> bucket_scan ->
//   partition+wprep -> csr_build+cvt -> agg1 -> gemm1(relu->h1b) -> agg2 ->
//   gemm2 -> d_out f32.  Fallback layout B (small ws): f32 gathers, h1 f32
//   staged in d_out.

typedef __attribute__((ext_vector_type(8))) short short8;
typedef __attribute__((ext_vector_type(4))) float float4_;

#define NBMAX 512  // max buckets (256 nodes each) -> N <= 131072

__device__ __forceinline__ unsigned short f2bf(float f) {
    unsigned int u = __float_as_uint(f);
    unsigned int r = (u + 0x7FFFu + ((u >> 16) & 1u)) >> 16;
    return (unsigned short)r;
}

// ---------------- phase 1a: per-block bucket histogram ---------------------
// Writes private histogram hist[blk][NB] (coalesced). No global atomics.
__global__ __launch_bounds__(256) void bucket_count(const int* __restrict__ dst, int E, int NB,
                                                    int* __restrict__ hist) {
    __shared__ int h[NBMAX];
    int tid = threadIdx.x;
    for (int b = tid; b < NB; b += 256) h[b] = 0;
    __syncthreads();
    int base = blockIdx.x * 4096;
    for (int i = 0; i < 16; i++) {
        int e = base + i * 256 + tid;
        if (e < E) atomicAdd(&h[dst[e] >> 8], 1);
    }
    __syncthreads();
    int* out = hist + (size_t)blockIdx.x * NB;
    for (int b = tid; b < NB; b += 256) out[b] = h[b];
}

// ---------------- phase 1b-1: cross-block scan per bucket ------------------
// Block b scans hist[0..nblk)[b] -> baseT[blk][b] (exclusive) + bucketCnt[b].
__global__ __launch_bounds__(256) void blk_scan(const int* __restrict__ hist, int nblk, int NB,
                                                int* __restrict__ baseT,
                                                int* __restrict__ bucketCnt) {
    __shared__ int sd[256];
    __shared__ int carryS;
    int b = blockIdx.x, tid = threadIdx.x;
    if (tid == 0) carryS = 0;
    __syncthreads();
    for (int c0 = 0; c0 < nblk; c0 += 256) {
        int i = c0 + tid;
        int v = (i < nblk) ? hist[(size_t)i * NB + b] : 0;
        sd[tid] = v;
        __syncthreads();
        for (int off = 1; off < 256; off <<= 1) {
            int x = sd[tid];
            int y = (tid >= off) ? sd[tid - off] : 0;
            __syncthreads();
            sd[tid] = x + y;
            __syncthreads();
        }
        int carry = carryS;
        if (i < nblk) baseT[(size_t)i * NB + b] = carry + sd[tid] - v;
        __syncthreads();
        if (tid == 255) carryS = carry + sd[255];
        __syncthreads();
    }
    if (tid == 0) bucketCnt[b] = carryS;
}

// ---------------- phase 1b-2: scan bucket totals (1 block) -----------------
__global__ __launch_bounds__(512) void bucket_scan(const int* __restrict__ bucketCnt, int NB,
                                                   int* __restrict__ bucketOffs) {
    __shared__ int sd[512];
    int t = threadIdx.x;
    int v = (t < NB) ? bucketCnt[t] : 0;
    sd[t] = v;
    __syncthreads();
    for (int off = 1; off < 512; off <<= 1) {
        int x = sd[t];
        int y = (t >= off) ? sd[t - off] : 0;
        __syncthreads();
        sd[t] = x + y;
        __syncthreads();
    }
    int excl = sd[t] - v;
    if (t <= NB) bucketOffs[t] = excl;  // bucketOffs[NB] = E sentinel
}

// ---------------- phase 1c: partition edges + (tail blocks) weight prep ----
// Write base per (block,bucket) from baseT (pure loads, no atomics);
// direct scatter (R8 style — proven faster than LDS restage, R11).
__global__ __launch_bounds__(256) void partition_wprep(
    const int* __restrict__ src, const int* __restrict__ dst, int E, int NB, int partBlocks,
    const int* __restrict__ bucketOffs, const int* __restrict__ baseT,
    unsigned int* __restrict__ bucketBuf,
    const float* __restrict__ Wn1, const float* __restrict__ Ws1,
    const float* __restrict__ bn1, const float* __restrict__ bs1,
    const float* __restrict__ Wn2, const float* __restrict__ Ws2,
    const float* __restrict__ bn2, const float* __restrict__ bs2,
    unsigned short* __restrict__ Bpre, float* __restrict__ biasPre) {
    int tid = threadIdx.x;
    if ((int)blockIdx.x >= partBlocks) {
        // ---- weight prep: f32 W -> bf16 pre-swizzled fragments ----
        int wb = blockIdx.x - partBlocks;  // [0,32)
        int l = wb >> 4;
        const float* Wn = l ? Wn2 : Wn1;
        const float* Ws = l ? Ws2 : Ws1;
        int fi = (wb & 15) * 256 + tid;
        int kt = fi >> 9;
        int nt = (fi >> 6) & 7;
        int lane = fi & 63;
        int o = nt * 16 + (lane & 15);
        int k = kt * 32 + (lane >> 4) * 8;
        const float* srcp = (k < 128) ? (Wn + o * 128 + k) : (Ws + o * 128 + (k - 128));
        short8 v;
#pragma unroll
        for (int j = 0; j < 8; j++) v[j] = (short)f2bf(srcp[j]);
        ((short8*)(Bpre + (size_t)l * 32768))[fi] = v;
        if ((wb & 15) == 0 && tid < 128) {
            const float* bn = l ? bn2 : bn1;
            const float* bs = l ? bs2 : bs1;
            biasPre[l * 128 + tid] = bn[tid] + bs[tid];
        }
        return;
    }
    __shared__ int cnt[NBMAX];
    __shared__ int gb[NBMAX];
    for (int b = tid; b < NB; b += 256) {
        cnt[b] = 0;
        gb[b] = bucketOffs[b] + baseT[(size_t)blockIdx.x * NB + b];
    }
    __syncthreads();
    int eb = blockIdx.x * 4096;
    unsigned int pk[16];
    int bk[16], rk[16];
    for (int i = 0; i < 16; i++) {
        int e = eb + i * 256 + tid;
        if (e < E) {
            int d = dst[e];
            bk[i] = d >> 8;
            pk[i] = (unsigned)src[e] | ((unsigned)(d & 255) << 24);
            rk[i] = atomicAdd(&cnt[bk[i]], 1);
        } else {
            bk[i] = -1;
        }
    }
    __syncthreads();
    for (int i = 0; i < 16; i++)
        if (bk[i] >= 0) bucketBuf[gb[bk[i]] + rk[i]] = pk[i];
}

// ---------------- phase 2: per-bucket CSR build + (tail blocks) x->bf16 ----
__global__ __launch_bounds__(256) void csrbuild_cvt(
    const unsigned int* __restrict__ bucketBuf, const int* __restrict__ bucketOffs,
    int N, int NB, int* __restrict__ deg, int* __restrict__ offs, int* __restrict__ sortedSrc,
    const float* __restrict__ xin, unsigned int* __restrict__ xb, int n2) {
    int tid = threadIdx.x;
    if ((int)blockIdx.x >= NB) {
        // ---- cvt: f32 [N,128] -> packed bf16 u32 [N,64], 8 u32/thread ----
        int cb = blockIdx.x - NB;
        int base = cb * 2048 + tid;
        if (xb) {
#pragma unroll
            for (int i = 0; i < 8; i++) {
                int t = base + i * 256;
                if (t < n2) {
                    float2 v = ((const float2*)xin)[t];
                    xb[t] = (unsigned)f2bf(v.x) | ((unsigned)f2bf(v.y) << 16);
                }
            }
        }
        return;
    }
    __shared__ int h[256];
    __shared__ int sc[256];
    __shared__ int cur[256];
    int b = blockIdx.x;
    int n0 = b << 8;
    int bo = bucketOffs[b];
    int cnt = bucketOffs[b + 1] - bo;
    h[tid] = 0;
    __syncthreads();
    for (int i = tid; i < cnt; i += 256) atomicAdd(&h[bucketBuf[bo + i] >> 24], 1);
    __syncthreads();
    int v = h[tid];
    sc[tid] = v;
    __syncthreads();
    for (int off = 1; off < 256; off <<= 1) {
        int x = sc[tid];
        int y = (tid >= off) ? sc[tid - off] : 0;
        __syncthreads();
        sc[tid] = x + y;
        __syncthreads();
    }
    int excl = sc[tid] - v;
    cur[tid] = bo + excl;
    int n = n0 + tid;
    if (n < N) {
        deg[n] = v;
        offs[n] = bo + excl;
    }
    __syncthreads();
    for (int i = tid; i < cnt; i += 256) {
        unsigned int pv = bucketBuf[bo + i];
        int pos = atomicAdd(&cur[pv >> 24], 1);
        sortedSrc[pos] = (int)(pv & 0xFFFFFFu);
    }
}

// ---------------- mean agg, bf16 source (wave/node, 16-deep, SGPR bases) ----
__global__ __launch_bounds__(256) void agg_bf16_kernel(
    const unsigned int* __restrict__ srcFeats,
    const int* __restrict__ deg, const int* __restrict__ offs,
    const int* __restrict__ sortedSrc,
    unsigned int* __restrict__ dst, int Nn) {
    int wave = threadIdx.x >> 6, lane = threadIdx.x & 63;
    int n = blockIdx.x * 4 + wave;
    if (n >= Nn) return;
    int d = deg[n], st = offs[n];
    float a0 = 0.f, a1 = 0.f;
    int j = 0;
    for (; j + 16 <= d; j += 16) {
        unsigned int uu[16];
#pragma unroll
        for (int u = 0; u < 16; u++) {
            int s = __builtin_amdgcn_readfirstlane(sortedSrc[st + j + u]);
            uu[u] = (srcFeats + (size_t)s * 64)[lane];
        }
#pragma unroll
        for (int u = 0; u < 16; u++) {
            a0 += __uint_as_float(uu[u] << 16);
            a1 += __uint_as_float(uu[u] & 0xFFFF0000u);
        }
    }
    for (; j + 8 <= d; j += 8) {
        unsigned int uu[8];
#pragma unroll
        for (int u = 0; u < 8; u++) {
            int s = __builtin_amdgcn_readfirstlane(sortedSrc[st + j + u]);
            uu[u] = (srcFeats + (size_t)s * 64)[lane];
        }
#pragma unroll
        for (int u = 0; u < 8; u++) {
            a0 += __uint_as_float(uu[u] << 16);
            a1 += __uint_as_float(uu[u] & 0xFFFF0000u);
        }
    }
    for (; j < d; j++) {
        int s = __builtin_amdgcn_readfirstlane(sortedSrc[st + j]);
        unsigned int u = (srcFeats + (size_t)s * 64)[lane];
        a0 += __uint_as_float(u << 16);
        a1 += __uint_as_float(u & 0xFFFF0000u);
    }
    float inv = 1.0f / (float)max(d, 1);
    dst[(size_t)n * 64 + lane] = (unsigned)f2bf(a0 * inv) | ((unsigned)f2bf(a1 * inv) << 16);
}

// ---------------- mean agg, f32 source (fallback layout B) ------------------
__global__ __launch_bounds__(256) void agg_f32_kernel(
    const float* __restrict__ srcFeats,
    const int* __restrict__ deg, const int* __restrict__ offs,
    const int* __restrict__ sortedSrc,
    unsigned int* __restrict__ dst, int Nn) {
    int wave = threadIdx.x >> 6, lane = threadIdx.x & 63;
    int n = blockIdx.x * 4 + wave;
    if (n >= Nn) return;
    int d = deg[n], st = offs[n];
    float a0 = 0.f, a1 = 0.f;
    int j = 0;
    for (; j + 8 <= d; j += 8) {
        float2 v[8];
#pragma unroll
        for (int u = 0; u < 8; u++) {
            int s = __builtin_amdgcn_readfirstlane(sortedSrc[st + j + u]);
            v[u] = ((const float2*)(srcFeats + (size_t)s * 128))[lane];
        }
#pragma unroll
        for (int u = 0; u < 8; u++) {
            a0 += v[u].x;
            a1 += v[u].y;
        }
    }
    for (; j < d; j++) {
        int s = __builtin_amdgcn_readfirstlane(sortedSrc[st + j]);
        float2 v = ((const float2*)(srcFeats + (size_t)s * 128))[lane];
        a0 += v.x;
        a1 += v.y;
    }
    float inv = 1.0f / (float)max(d, 1);
    dst[(size_t)n * 64 + lane] = (unsigned)f2bf(a0 * inv) | ((unsigned)f2bf(a1 * inv) << 16);
}

// ---------------- fused GEMM: out = act([Aagg|Aself] @ B^T + bias) ---------
// Aagg: [N,128] bf16. Aself: bf16 (selfF32=0) or f32 (selfF32=1).
// Bpre: 64KB pre-swizzled bf16 fragments; biasPre: 128 f32 (bn+bs).
// Out: bf16 (outBf16=1) or f32. MFMA 16x16x32 bf16; 4 waves, 128 rows/block.
// Out may alias Aself (fallback layer 2): each wave reads only its own 32
// rows before writing them -> safe. (No __restrict__ on Aself/Out.)
__global__ __launch_bounds__(256) void gemm_kernel(
    const unsigned short* __restrict__ Aagg, const void* Aself,
    const unsigned short* __restrict__ Bpre, const float* __restrict__ biasPre,
    void* Out, int relu, int selfF32, int outBf16, int Nrows) {
    __shared__ unsigned short ldsB[8 * 8 * 64 * 8];  // 64 KB
    __shared__ float biasS[128];
    int tid = threadIdx.x;

    // Pure coalesced copy: Bpre is already bf16 in fragment order.
#pragma unroll
    for (int i = 0; i < 16; i++) {
        int fi = tid + 256 * i;
        ((short8*)ldsB)[fi] = ((const short8*)Bpre)[fi];
    }
    if (tid < 128) biasS[tid] = biasPre[tid];
    __syncthreads();

    int wave = tid >> 6, lane = tid & 63;
    int quad = lane >> 4, mr = lane & 15;
    int rowBase = blockIdx.x * 128 + wave * 32;

    float4_ acc[2][8];
    float4_ z = {0.f, 0.f, 0.f, 0.f};
    for (int mt = 0; mt < 2; mt++)
        for (int nt = 0; nt < 8; nt++) acc[mt][nt] = z;

    for (int kt = 0; kt < 8; kt++) {
        int kk = (kt & 3) * 32 + quad * 8;
        short8 a[2];
        for (int mt = 0; mt < 2; mt++) {
            int row = rowBase + mt * 16 + mr;
            if (row >= Nrows) row = Nrows - 1;  // in-bounds; result discarded
            if (kt < 4) {
                a[mt] = *(const short8*)(Aagg + (size_t)row * 128 + kk);
            } else if (selfF32) {
                const float* p = (const float*)Aself + (size_t)row * 128 + kk;
                float4_ f0 = *(const float4_*)p;
                float4_ f1 = *(const float4_*)(p + 4);
                short8 t;
#pragma unroll
                for (int j = 0; j < 4; j++) {
                    t[j] = (short)f2bf(f0[j]);
                    t[4 + j] = (short)f2bf(f1[j]);
                }
                a[mt] = t;
            } else {
                a[mt] = *(const short8*)((const unsigned short*)Aself + (size_t)row * 128 + kk);
            }
        }
        for (int nt = 0; nt < 8; nt++) {
            short8 b = *(const short8*)(ldsB + ((size_t)(kt * 8 + nt) * 64 + lane) * 8);
            acc[0][nt] = __builtin_amdgcn_mfma_f32_16x16x32_bf16(a[0], b, acc[0][nt], 0, 0, 0);
            acc[1][nt] = __builtin_amdgcn_mfma_f32_16x16x32_bf16(a[1], b, acc[1][nt], 0, 0, 0);
        }
    }

    // C/D layout: col = lane&15, row = (lane>>4)*4 + reg
    for (int mt = 0; mt < 2; mt++) {
        for (int nt = 0; nt < 8; nt++) {
            int col = nt * 16 + mr;
            float bv = biasS[col];
            for (int r = 0; r < 4; r++) {
                int row = rowBase + mt * 16 + quad * 4 + r;
                if (row < Nrows) {
                    float v = acc[mt][nt][r] + bv;
                    if (relu) v = fmaxf(v, 0.f);
                    if (outBf16)
                        ((unsigned short*)Out)[(size_t)row * 128 + col] = f2bf(v);
                    else
                        ((float*)Out)[(size_t)row * 128 + col] = v;
                }
            }
        }
    }
}

extern "C" void kernel_launch(void* const* d_in, const int* in_sizes, int n_in,
                              void* d_out, int out_size, void* d_ws, size_t ws_size,
                              hipStream_t stream) {
    const float* x = (const float*)d_in[0];
    const int* ei = (const int*)d_in[1];
    const float* Wn1 = (const float*)d_in[2];
    const float* bn1 = (const float*)d_in[3];
    const float* Ws1 = (const float*)d_in[4];
    const float* bs1 = (const float*)d_in[5];
    const float* Wn2 = (const float*)d_in[6];
    const float* bn2 = (const float*)d_in[7];
    const float* Ws2 = (const float*)d_in[8];
    const float* bs2 = (const float*)d_in[9];

    const int N = in_sizes[0] / 128;
    const int E = in_sizes[1] / 2;
    const int* srcI = ei;
    const int* dstI = ei + E;
    const int NB = (N + 255) >> 8;       // <= NBMAX for N <= 131072
    const int ebBlocks = (E + 4095) / 4096;

    char* ws = (char*)d_ws;
    size_t off = 0;
    auto alloc = [&](size_t bytes) -> void* {
        void* p = ws + off;
        off += (bytes + 255) & ~(size_t)255;
        return p;
    };
    int* deg = (int*)alloc((size_t)N * 4);
    int* offs = (int*)alloc((size_t)N * 4);
    int* bucketCnt = (int*)alloc((NBMAX + 1) * 4);
    int* bucketOffs = (int*)alloc((NBMAX + 1) * 4);
    int* hist = (int*)alloc((size_t)ebBlocks * NB * 4);
    int* baseT = (int*)alloc((size_t)ebBlocks * NB * 4);
    unsigned short* Bpre = (unsigned short*)alloc(2 * 32768 * 2);
    float* biasPre = (float*)alloc(2 * 128 * 4);
    int* sortedSrc = (int*)alloc((size_t)E * 4);
    unsigned short* Aagg = (unsigned short*)alloc((size_t)N * 128 * 2);
    size_t baseNeed = off;
    size_t bf16Buf = ((size_t)N * 128 * 2 + 255) & ~(size_t)255;
    bool bigWs = (ws_size >= baseNeed + 2 * bf16Buf);
    unsigned int* xb = nullptr;
    unsigned short* h1b = nullptr;
    if (bigWs) {
        xb = (unsigned int*)alloc((size_t)N * 128 * 2);
        h1b = (unsigned short*)alloc((size_t)N * 128 * 2);
    }
    // bucketBuf (E u32, 6.4 MB) aliases Aagg (dead until agg1)
    unsigned int* bucketBuf = (unsigned int*)Aagg;

    // ---- CSR build (atomic-free bucketing) + overlapped wprep/cvt ----
    int n2 = N * 64;
    int cvtBlocks = bigWs ? (n2 + 2047) / 2048 : 0;
    bucket_count<<<ebBlocks, 256, 0, stream>>>(dstI, E, NB, hist);
    blk_scan<<<NB, 256, 0, stream>>>(hist, ebBlocks, NB, baseT, bucketCnt);
    bucket_scan<<<1, 512, 0, stream>>>(bucketCnt, NB, bucketOffs);
    partition_wprep<<<ebBlocks + 32, 256, 0, stream>>>(
        srcI, dstI, E, NB, ebBlocks, bucketOffs, baseT, bucketBuf,
        Wn1, Ws1, bn1, bs1, Wn2, Ws2, bn2, bs2, Bpre, biasPre);
    csrbuild_cvt<<<NB + cvtBlocks, 256, 0, stream>>>(bucketBuf, bucketOffs, N, NB, deg, offs,
                                                     sortedSrc, x, xb, n2);

    int aggBlocks = (N + 3) / 4;
    int gemmBlocks = (N + 127) / 128;

    if (bigWs) {
        // Layout A: all gathers bf16 (256 B/row)
        agg_bf16_kernel<<<aggBlocks, 256, 0, stream>>>(xb, deg, offs, sortedSrc,
                                                       (unsigned int*)Aagg, N);
        gemm_kernel<<<gemmBlocks, 256, 0, stream>>>(Aagg, xb, Bpre, biasPre, h1b, 1, 0, 1, N);
        agg_bf16_kernel<<<aggBlocks, 256, 0, stream>>>((const unsigned int*)h1b, deg, offs,
                                                       sortedSrc, (unsigned int*)Aagg, N);
        gemm_kernel<<<gemmBlocks, 256, 0, stream>>>(Aagg, h1b, Bpre + 32768, biasPre + 128,
                                                    d_out, 0, 0, 0, N);
    } else {
        // Layout B: f32 gathers, h1 f32 staged in d_out
        float* h1 = (float*)d_out;
        agg_f32_kernel<<<aggBlocks, 256, 0, stream>>>(x, deg, offs, sortedSrc,
                                                      (unsigned int*)Aagg, N);
        gemm_kernel<<<gemmBlocks, 256, 0, stream>>>(Aagg, x, Bpre, biasPre, h1, 1, 1, 0, N);
        agg_f32_kernel<<<aggBlocks, 256, 0, stream>>>(h1, deg, offs, sortedSrc,
                                                      (unsigned int*)Aagg, N);
        gemm_kernel<<<gemmBlocks, 256, 0, stream>>>(Aagg, h1, Bpre + 32768, biasPre + 128,
                                                    d_out, 0, 1, 0, N);
    }
}